// Round 11
// baseline (116.255 us; speedup 1.0000x reference)
//
#include <hip/hip_runtime.h>
#include <stdint.h>
#include <math.h>

#define NCLS 81
#define NFG  80
#define NPI  1024
#define NIMG 8
#define DETS 100
#define SCORE_T 0.05f
#define NMS_T   0.5f
#define NCAND   (NFG * DETS)   // 8000
#define CAND_CAP 1024
#define ROWS 64                // rows per decode_filter block
#define NPID (NIMG * NFG)      // 640

static constexpr float BBOX_CLIP = 4.1351665567423557f; // log(1000/16)

__device__ __forceinline__ float rlf(float v, int i) {
#if __has_builtin(__builtin_amdgcn_readlane)
    return __uint_as_float((unsigned)__builtin_amdgcn_readlane((int)__float_as_uint(v), i));
#else
    return __shfl(v, i, 64);
#endif
}

// ============ Kernel A: fused softmax + filter + decode + append ============
// key = score_bits<<32 | (1023-m)<<10 | append_pos   (upper 54 bits unique)
__global__ __launch_bounds__(256) void decode_filter(
    const float* __restrict__ logits, const float* __restrict__ boxreg,
    const float* __restrict__ props, const int* __restrict__ hptr,
    const int* __restrict__ wptr, int* __restrict__ cnt,
    unsigned long long* __restrict__ key8, float4* __restrict__ box16, int M)
{
    __shared__ float tile[ROWS * NCLS];   // 20736 B
    __shared__ float mx[ROWS], dn[ROWS];
    int t = threadIdx.x;
    int rbase = blockIdx.x * ROWS;

    for (int idx = t; idx < ROWS * NCLS; idx += 256)
        tile[idx] = logits[(size_t)rbase * NCLS + idx];
    __syncthreads();
    if (t < ROWS) {
        const float* r = tile + t * NCLS;
        float m = r[0];
        #pragma unroll
        for (int j = 1; j < NCLS; ++j) m = fmaxf(m, r[j]);
        float s = 0.f;
        #pragma unroll
        for (int j = 0; j < NCLS; ++j) s += expf(r[j] - m);
        mx[t] = m; dn[t] = s;
    }
    __syncthreads();

    float W1 = (float)(*wptr - 1);
    float H1 = (float)(*hptr - 1);

    for (int o = t; o < ROWS * NFG; o += 256) {
        int r  = o & 63;
        int cc = o >> 6;                  // fg class 0..79
        float pr = expf(tile[r * NCLS + (cc + 1)] - mx[r]) / dn[r];
        if (pr > SCORE_T) {
            int row = rbase + r;          // global proposal row
            int img = row >> 10;
            int m   = row & 1023;
            int pid = img * NFG + cc;
            int cls = cc + 1;
            const float4 pb = *(const float4*)(props + (size_t)row * 4);
            float x1 = pb.x, y1 = pb.y, x2 = pb.z, y2 = pb.w;
            float w  = x2 - x1 + 1.0f, h = y2 - y1 + 1.0f;
            float cx = x1 + 0.5f * w,  cy = y1 + 0.5f * h;
            const float4 rc = *(const float4*)(boxreg + (size_t)row * (4 * NCLS) + 4 * cls);
            float dx = rc.x / 10.0f, dy = rc.y / 10.0f;
            float dw = fminf(rc.z / 5.0f, BBOX_CLIP);
            float dh = fminf(rc.w / 5.0f, BBOX_CLIP);
            float pcx = dx * w + cx, pcy = dy * h + cy;
            float pw = expf(dw) * w, ph = expf(dh) * h;
            float bx1 = fminf(fmaxf(pcx - 0.5f * pw, 0.f), W1);
            float by1 = fminf(fmaxf(pcy - 0.5f * ph, 0.f), H1);
            float bx2 = fminf(fmaxf(pcx + 0.5f * pw - 1.0f, 0.f), W1);
            float by2 = fminf(fmaxf(pcy + 0.5f * ph - 1.0f, 0.f), H1);
            int pos = atomicAdd(&cnt[pid], 1);   // < 1024 structurally
            key8[(size_t)pid * CAND_CAP + pos] =
                ((unsigned long long)__float_as_uint(pr) << 32)
              | ((unsigned)(NPI - 1 - m) << 10) | (unsigned)pos;
            box16[(size_t)pid * CAND_CAP + pos] = make_float4(bx1, by1, bx2, by2);
        }
    }
}

// ============ Kernel B: per-(img,class) NMS, 4 independent waves/block ============
__global__ __launch_bounds__(256) void wave_nms(
    const int* __restrict__ cnt, const unsigned long long* __restrict__ key8,
    const float4* __restrict__ box16, int* __restrict__ out_cnt,
    float* __restrict__ out_score, unsigned* __restrict__ out_key,
    float* __restrict__ out_box)
{
    __shared__ unsigned long long skey_lds[4][CAND_CAP];   // rare path only (32KB)
    __shared__ unsigned long long remv_lds[4][16];
    __shared__ int base_lds[4][17];

    int wid  = threadIdx.x >> 6;
    int lane = threadIdx.x & 63;
    int pid  = blockIdx.x * 4 + wid;     // 0..639
    int c    = pid % NFG;

    int n = cnt[pid];
    if (n > CAND_CAP) n = CAND_CAP;
    const unsigned long long* kk = key8 + (size_t)pid * CAND_CAP;
    const float4* bb = box16 + (size_t)pid * CAND_CAP;

    if (n <= 64) {
        // ---------------- hot path: registers only, zero barriers ----------------
        unsigned long long k = (lane < n) ? kk[lane] : 0ULL;
        #pragma unroll
        for (int kk2 = 2; kk2 <= 64; kk2 <<= 1) {
            #pragma unroll
            for (int j = kk2 >> 1; j > 0; j >>= 1) {
                unsigned long long o = __shfl_xor(k, j, 64);
                bool take_max = (((lane & kk2) == 0) == ((lane & j) == 0));
                k = take_max ? (k > o ? k : o) : (k < o ? k : o);
            }
        }
        bool valid = (lane < n);
        float bx1 = 0.f, by1 = 0.f, bx2 = 0.f, by2 = 0.f, area = 0.f;
        if (valid) {
            float4 b = bb[(int)(k & 0x3FFu)];
            bx1 = b.x; by1 = b.y; bx2 = b.z; by2 = b.w;
            area = (bx2 - bx1 + 1.f) * (by2 - by1 + 1.f);
        }
        unsigned long long sup = 0ULL;
        for (int i = 0; i < n; ++i) {
            if ((sup >> i) & 1ULL) continue;       // wave-uniform skip
            float ax1 = rlf(bx1, i), ay1 = rlf(by1, i);
            float ax2 = rlf(bx2, i), ay2 = rlf(by2, i);
            float aarea = rlf(area, i);
            bool s = false;
            if (valid && lane > i) {
                float xx1 = fmaxf(ax1, bx1), yy1 = fmaxf(ay1, by1);
                float xx2 = fminf(ax2, bx2), yy2 = fminf(ay2, by2);
                float iw = fmaxf(xx2 - xx1 + 1.f, 0.f);
                float ih = fmaxf(yy2 - yy1 + 1.f, 0.f);
                float inter = iw * ih;
                s = inter / (aarea + area - inter) > NMS_T;
            }
            sup |= __ballot(s);
        }
        bool kept = valid && !((sup >> lane) & 1ULL);
        unsigned long long keptm = __ballot(kept);
        int rank = __popcll(keptm & ((1ULL << lane) - 1ULL));
        if (kept && rank < DETS) {
            int slot = pid * DETS + rank;
            out_score[slot] = __uint_as_float((unsigned)(k >> 32));
            out_key[slot] = (unsigned)(c * NPI + lane);   // lane = sorted rank
            out_box[slot * 4 + 0] = bx1; out_box[slot * 4 + 1] = by1;
            out_box[slot * 4 + 2] = bx2; out_box[slot * 4 + 3] = by2;
        }
        if (lane == 0) {
            int tot = __popcll(keptm);
            out_cnt[pid] = tot < DETS ? tot : DETS;
        }
        return;
    }

    // ---------------- rare path: 64 < n <= 1024, single wave, no barriers -------
    // rank-order sort into per-wave LDS (keys' upper bits unique)
    for (int i = lane; i < n; i += 64) {
        unsigned long long ki = kk[i];
        int r = 0;
        for (int j = 0; j < n; ++j) r += (kk[j] > ki) ? 1 : 0;
        skey_lds[wid][r] = ki;
    }
    if (lane < 16) remv_lds[wid][lane] = 0ULL;
    __threadfence_block();   // drain LDS writes (no cross-wave barrier)

    int nch = (n + 63) >> 6;
    for (int a = 0; a < nch; ++a) {
        int ea = a * 64 + lane;
        bool va = ea < n;
        float bx1 = 0.f, by1 = 0.f, bx2 = 0.f, by2 = 0.f, area = 0.f;
        if (va) {
            float4 b = bb[(int)(skey_lds[wid][ea] & 0x3FFu)];
            bx1 = b.x; by1 = b.y; bx2 = b.z; by2 = b.w;
            area = (bx2 - bx1 + 1.f) * (by2 - by1 + 1.f);
        }
        unsigned long long sup = remv_lds[wid][a];
        int lim = (n - a * 64 < 64) ? (n - a * 64) : 64;
        for (int i = 0; i < lim; ++i) {
            if ((sup >> i) & 1ULL) continue;
            float ax1 = rlf(bx1, i), ay1 = rlf(by1, i);
            float ax2 = rlf(bx2, i), ay2 = rlf(by2, i);
            float aarea = rlf(area, i);
            bool s = false;
            if (va && lane > i) {
                float xx1 = fmaxf(ax1, bx1), yy1 = fmaxf(ay1, by1);
                float xx2 = fminf(ax2, bx2), yy2 = fminf(ay2, by2);
                float iw = fmaxf(xx2 - xx1 + 1.f, 0.f);
                float ih = fmaxf(yy2 - yy1 + 1.f, 0.f);
                float inter = iw * ih;
                s = inter / (aarea + area - inter) > NMS_T;
            }
            sup |= __ballot(s);
        }
        if (lane == 0) remv_lds[wid][a] = sup;
        for (int b2 = a + 1; b2 < nch; ++b2) {
            int eb = b2 * 64 + lane;
            bool vb = eb < n;
            float cx1 = 0.f, cy1 = 0.f, cx2 = 0.f, cy2 = 0.f, carea = 0.f;
            if (vb) {
                float4 b = bb[(int)(skey_lds[wid][eb] & 0x3FFu)];
                cx1 = b.x; cy1 = b.y; cx2 = b.z; cy2 = b.w;
                carea = (cx2 - cx1 + 1.f) * (cy2 - cy1 + 1.f);
            }
            unsigned long long supb = 0ULL;
            for (int i = 0; i < lim; ++i) {
                if ((sup >> i) & 1ULL) continue;   // only alive pivots suppress
                float ax1 = rlf(bx1, i), ay1 = rlf(by1, i);
                float ax2 = rlf(bx2, i), ay2 = rlf(by2, i);
                float aarea = rlf(area, i);
                bool s = false;
                if (vb) {
                    float xx1 = fmaxf(ax1, cx1), yy1 = fmaxf(ay1, cy1);
                    float xx2 = fminf(ax2, cx2), yy2 = fminf(ay2, cy2);
                    float iw = fmaxf(xx2 - xx1 + 1.f, 0.f);
                    float ih = fmaxf(yy2 - yy1 + 1.f, 0.f);
                    float inter = iw * ih;
                    s = inter / (aarea + carea - inter) > NMS_T;
                }
                supb |= __ballot(s);
            }
            if (lane == 0) remv_lds[wid][b2] |= supb;
            __threadfence_block();
        }
        __threadfence_block();
    }

    // output: ranks among kept, sorted order
    if (lane == 0) {
        base_lds[wid][0] = 0;
        for (int ch = 0; ch < nch; ++ch) {
            int rem = n - ch * 64;
            unsigned long long vm = (rem >= 64) ? ~0ULL : ((1ULL << rem) - 1ULL);
            base_lds[wid][ch + 1] = base_lds[wid][ch]
                                  + __popcll(~remv_lds[wid][ch] & vm);
        }
    }
    __threadfence_block();
    for (int e = lane; e < n; e += 64) {
        int ch = e >> 6;
        unsigned long long rm = remv_lds[wid][ch];
        int rem = n - ch * 64;
        unsigned long long vm = (rem >= 64) ? ~0ULL : ((1ULL << rem) - 1ULL);
        bool kept = !((rm >> (e & 63)) & 1ULL);
        if (kept) {
            int r = base_lds[wid][ch]
                  + __popcll(~rm & vm & ((1ULL << (e & 63)) - 1ULL));
            if (r < DETS) {
                unsigned long long ki = skey_lds[wid][e];
                float4 b = bb[(int)(ki & 0x3FFu)];
                int slot = pid * DETS + r;
                out_score[slot] = __uint_as_float((unsigned)(ki >> 32));
                out_key[slot] = (unsigned)(c * NPI + e);
                out_box[slot * 4 + 0] = b.x; out_box[slot * 4 + 1] = b.y;
                out_box[slot * 4 + 2] = b.z; out_box[slot * 4 + 3] = b.w;
            }
        }
    }
    if (lane == 0) {
        int tot = base_lds[wid][nch];
        out_cnt[pid] = tot < DETS ? tot : DETS;
    }
}

// ============ Kernel C: per-image top-100, radix-select + rank write (proven) ====
__device__ __forceinline__ void suffix_select256(
    unsigned* hist, unsigned* wtot, int K, int* outB, unsigned* outAbove)
{
    int t = threadIdx.x, lane = t & 63, w = t >> 6;
    unsigned loc[16]; unsigned ps = 0;
    #pragma unroll
    for (int j = 0; j < 16; ++j) { loc[j] = hist[t * 16 + j]; ps += loc[j]; }
    unsigned v = ps;
    #pragma unroll
    for (int off = 1; off < 64; off <<= 1) {
        unsigned u = __shfl_down(v, off, 64);
        v += (lane + off < 64) ? u : 0u;
    }
    if (lane == 0) wtot[w] = v;
    __syncthreads();
    unsigned woff = 0;
    for (int w2 = w + 1; w2 < 4; ++w2) woff += wtot[w2];
    unsigned base = v + woff - ps;
    unsigned suf = 0;
    #pragma unroll
    for (int j = 15; j >= 0; --j) {
        unsigned A = base + suf;
        if ((int)A < K && (int)(A + loc[j]) >= K) { *outB = t * 16 + j; *outAbove = A; }
        suf += loc[j];
    }
    __syncthreads();
}

__global__ __launch_bounds__(256) void topk_merge(
    const int* __restrict__ cnts, const float* __restrict__ escore,
    const unsigned* __restrict__ ekey, const float* __restrict__ ebox,
    float* __restrict__ out)
{
    int img = blockIdx.x;
    __shared__ unsigned sc[NCAND];
    __shared__ unsigned hist[4096];
    __shared__ unsigned long long cand[CAND_CAP];
    __shared__ int scnts[NFG];
    __shared__ unsigned wtot[4];
    __shared__ int sB1, sB2, sNc;
    __shared__ unsigned sAb1, sAb2;

    int t = threadIdx.x;
    if (t < NFG) scnts[t] = cnts[img * NFG + t];
    if (t == 0) { sB1 = 0; sB2 = 0; sNc = 0; sAb1 = 0; sAb2 = 0; }
    for (int i = t; i < 4096; i += 256) hist[i] = 0;
    __syncthreads();

    for (int p = t; p < NCAND; p += 256) {
        unsigned fb = 0;
        if ((p % DETS) < scnts[p / DETS]) fb = __float_as_uint(escore[img * NCAND + p]);
        sc[p] = fb;
        if (fb) atomicAdd(&hist[fb >> 19], 1u);
    }
    __syncthreads();
    suffix_select256(hist, wtot, DETS, &sB1, &sAb1);
    int B1 = sB1; unsigned ab1 = sAb1;

    for (int i = t; i < 4096; i += 256) hist[i] = 0;
    __syncthreads();
    for (int p = t; p < NCAND; p += 256) {
        unsigned fb = sc[p];
        if (fb && (int)(fb >> 19) == B1) atomicAdd(&hist[(fb >> 7) & 0xFFFu], 1u);
    }
    __syncthreads();
    suffix_select256(hist, wtot, DETS - (int)ab1, &sB2, &sAb2);
    int B2 = sB2;

    for (int p = t; p < NCAND; p += 256) {
        unsigned fb = sc[p];
        if (fb) {
            int d1 = (int)(fb >> 19);
            bool ok = d1 > B1 || (d1 == B1 && (int)((fb >> 7) & 0xFFFu) >= B2);
            if (ok) {
                int pos = atomicAdd(&sNc, 1);
                if (pos < CAND_CAP) {
                    unsigned fk = ekey[img * NCAND + p];
                    cand[pos] = ((unsigned long long)fb << 32)
                              | (((0x1FFFFu - fk) << 13) | (unsigned)p);
                }
            }
        }
    }
    __syncthreads();
    int nc = sNc < CAND_CAP ? sNc : CAND_CAP;

    float* oScore = out;
    float* oBox   = out + NIMG * DETS;
    float* oLab   = out + NIMG * DETS * 5;

    for (int k = t; k < DETS; k += 256) {
        if (k >= nc) {
            int o = img * DETS + k;
            oScore[o] = 0.f;
            oBox[o * 4 + 0] = 0.f; oBox[o * 4 + 1] = 0.f;
            oBox[o * 4 + 2] = 0.f; oBox[o * 4 + 3] = 0.f;
            oLab[o] = 0.f;
        }
    }

    for (int i = t; i < nc; i += 256) {
        unsigned long long ki = cand[i];
        int r = 0;
        for (int j = 0; j < nc; ++j) r += (cand[j] > ki) ? 1 : 0;
        if (r < DETS) {
            float scv = __uint_as_float((unsigned)(ki >> 32));
            unsigned low = (unsigned)(ki & 0xFFFFFFFFu);
            unsigned flatkey = 0x1FFFFu - ((low >> 13) & 0x1FFFFu);
            int p = (int)(low & 0x1FFFu);
            int gp = img * NCAND + p;
            int o = img * DETS + r;
            oScore[o] = scv;
            oBox[o * 4 + 0] = ebox[gp * 4 + 0];
            oBox[o * 4 + 1] = ebox[gp * 4 + 1];
            oBox[o * 4 + 2] = ebox[gp * 4 + 2];
            oBox[o * 4 + 3] = ebox[gp * 4 + 3];
            oLab[o] = (float)((flatkey >> 10) + 1);
        }
    }
}

extern "C" void kernel_launch(void* const* d_in, const int* in_sizes, int n_in,
                              void* d_out, int out_size, void* d_ws, size_t ws_size,
                              hipStream_t stream) {
    const float* logits = (const float*)d_in[0];
    const float* boxreg = (const float*)d_in[1];
    const float* props  = (const float*)d_in[2];
    const int*   hptr   = (const int*)d_in[3];
    const int*   wptr   = (const int*)d_in[4];
    float* out = (float*)d_out;
    int M = in_sizes[0] / NCLS; // 8192

    char* ws = (char*)d_ws;
    int*                cnt    = (int*)ws;                 ws += (size_t)NPID * sizeof(int);
    int*                gcnt   = (int*)ws;                 ws += (size_t)NPID * sizeof(int);
    ws = (char*)(((uintptr_t)ws + 15) & ~(uintptr_t)15);
    unsigned long long* key8   = (unsigned long long*)ws;  ws += (size_t)NPID * CAND_CAP * 8;
    float4*             box16  = (float4*)ws;              ws += (size_t)NPID * CAND_CAP * 16;
    float*              escore = (float*)ws;               ws += (size_t)NIMG * NCAND * sizeof(float);
    unsigned*           ekey   = (unsigned*)ws;            ws += (size_t)NIMG * NCAND * sizeof(unsigned);
    float*              ebox   = (float*)ws;               ws += (size_t)NIMG * NCAND * 4 * sizeof(float);

    hipMemsetAsync(cnt, 0, (size_t)NPID * sizeof(int), stream);
    decode_filter<<<M / ROWS, 256, 0, stream>>>(
        logits, boxreg, props, hptr, wptr, cnt, key8, box16, M);
    wave_nms<<<NPID / 4, 256, 0, stream>>>(
        cnt, key8, box16, gcnt, escore, ekey, ebox);
    topk_merge<<<NIMG, 256, 0, stream>>>(gcnt, escore, ekey, ebox, out);
}

// Round 12
// 72.790 us; speedup vs baseline: 1.5971x; 1.5971x over previous
//
#include <hip/hip_runtime.h>
#include <stdint.h>
#include <math.h>

#define NCLS 81
#define NFG  80
#define NPI  1024
#define NIMG 8
#define DETS 100
#define SCORE_T 0.05f
#define NMS_T   0.5f
#define NCAND   (NFG * DETS)   // 8000
#define CAND_CAP 1024
#define FASTN 256              // block bitmask-NMS path limit
#define ROWS 64                // rows per softmax block

static constexpr float BBOX_CLIP = 4.1351665567423557f; // log(1000/16)

// ---------------- Kernel 1: softmax -> transposed prob matrix (R5, proven) ----
__global__ __launch_bounds__(256) void softmax_probT(
    const float* __restrict__ logits, float* __restrict__ probT, int M)
{
    __shared__ float tile[ROWS * NCLS];
    __shared__ float mx[ROWS], dn[ROWS];
    int t = threadIdx.x;
    int rbase = blockIdx.x * ROWS;
    for (int idx = t; idx < ROWS * NCLS; idx += 256)
        tile[idx] = logits[(size_t)rbase * NCLS + idx];
    __syncthreads();
    if (t < ROWS) {
        const float* r = tile + t * NCLS;
        float m = r[0];
        #pragma unroll
        for (int j = 1; j < NCLS; ++j) m = fmaxf(m, r[j]);
        float s = 0.f;
        #pragma unroll
        for (int j = 0; j < NCLS; ++j) s += expf(r[j] - m);
        mx[t] = m; dn[t] = s;
    }
    __syncthreads();
    for (int o = t; o < ROWS * NFG; o += 256) {
        int r = o & 63;
        int c = o >> 6;
        probT[(size_t)c * M + rbase + r] = expf(tile[r * NCLS + (c + 1)] - mx[r]) / dn[r];
    }
}

// ---------------- Kernel 2: per-(image,class) NMS (R5, proven) ----------------
struct ShP2 {
    float box[NPI][4];                         // 16KB (by proposal id)
    unsigned long long key[NPI];               // 8KB
    int keep[NPI];                             // 4KB
    float sbox[FASTN][4];                      // 4KB
    float sarea[FASTN];                        // 1KB
    unsigned long long mask[FASTN][FASTN/64];  // 8KB
    unsigned long long keepw[FASTN/64];
    unsigned wpre[4];
};

__global__ __launch_bounds__(256) void per_class_nms(
    const float* __restrict__ probT, const float* __restrict__ boxreg,
    const float* __restrict__ props, const int* __restrict__ hptr,
    const int* __restrict__ wptr, int* __restrict__ out_cnt,
    float* __restrict__ out_score, unsigned* __restrict__ out_key,
    float* __restrict__ out_box, int M)
{
    int pid = blockIdx.x;           // 0..639
    int img = pid / NFG;
    int c   = pid % NFG;
    int cls = c + 1;

    __shared__ ShP2 sp;
    __shared__ int cnt;
    int t = threadIdx.x;
    float W1 = (float)(*wptr - 1);
    float H1 = (float)(*hptr - 1);

    if (t == 0) cnt = 0;
    for (int i = t; i < NPI; i += 256) sp.key[i] = 0ULL;
    __syncthreads();
    {
        const float4 pv = *(const float4*)(probT + (size_t)c * M + img * NPI + 4 * t);
        float pr[4] = {pv.x, pv.y, pv.z, pv.w};
        #pragma unroll
        for (int j = 0; j < 4; ++j) {
            if (pr[j] > SCORE_T) {
                int m = 4 * t + j;
                int g = img * NPI + m;
                const float4 pb = *(const float4*)(props + (size_t)g * 4);
                float x1 = pb.x, y1 = pb.y, x2 = pb.z, y2 = pb.w;
                float w  = x2 - x1 + 1.0f, h = y2 - y1 + 1.0f;
                float cx = x1 + 0.5f * w,  cy = y1 + 0.5f * h;
                const float4 rc = *(const float4*)(boxreg + (size_t)g * (4 * NCLS) + 4 * cls);
                float dx = rc.x / 10.0f, dy = rc.y / 10.0f;
                float dw = fminf(rc.z / 5.0f, BBOX_CLIP);
                float dh = fminf(rc.w / 5.0f, BBOX_CLIP);
                float pcx = dx * w + cx, pcy = dy * h + cy;
                float pw = expf(dw) * w, ph = expf(dh) * h;
                float bx1 = fminf(fmaxf(pcx - 0.5f * pw, 0.f), W1);
                float by1 = fminf(fmaxf(pcy - 0.5f * ph, 0.f), H1);
                float bx2 = fminf(fmaxf(pcx + 0.5f * pw - 1.0f, 0.f), W1);
                float by2 = fminf(fmaxf(pcy + 0.5f * ph - 1.0f, 0.f), H1);
                sp.box[m][0] = bx1; sp.box[m][1] = by1;
                sp.box[m][2] = bx2; sp.box[m][3] = by2;
                int p = atomicAdd(&cnt, 1);
                sp.key[p] = ((unsigned long long)__float_as_uint(pr[j]) << 32)
                          | (unsigned)(NPI - 1 - m);
            }
        }
    }
    __syncthreads();
    int n = cnt;

    if (n <= 64) {
        if (t < 64) {
            int lane = t;
            unsigned long long k = (lane < n) ? sp.key[lane] : 0ULL;
            #pragma unroll
            for (int kk = 2; kk <= 64; kk <<= 1) {
                #pragma unroll
                for (int j = kk >> 1; j > 0; j >>= 1) {
                    unsigned long long o = __shfl_xor(k, j, 64);
                    bool take_max = (((lane & kk) == 0) == ((lane & j) == 0));
                    k = take_max ? (k > o ? k : o) : (k < o ? k : o);
                }
            }
            bool valid = (lane < n);
            float bx1 = 0.f, by1 = 0.f, bx2 = 0.f, by2 = 0.f, area = 0.f;
            if (valid) {
                int mi = NPI - 1 - (int)(k & 0xFFFFFFFFu);
                bx1 = sp.box[mi][0]; by1 = sp.box[mi][1];
                bx2 = sp.box[mi][2]; by2 = sp.box[mi][3];
                area = (bx2 - bx1 + 1.f) * (by2 - by1 + 1.f);
            }
            unsigned long long sup = 0ULL;
            for (int i = 0; i < n; ++i) {
                bool alive = !((sup >> i) & 1ULL);
                float ax1 = __shfl(bx1, i, 64), ay1 = __shfl(by1, i, 64);
                float ax2 = __shfl(bx2, i, 64), ay2 = __shfl(by2, i, 64);
                float aarea = __shfl(area, i, 64);
                bool s = false;
                if (alive && valid && lane > i) {
                    float xx1 = fmaxf(ax1, bx1), yy1 = fmaxf(ay1, by1);
                    float xx2 = fminf(ax2, bx2), yy2 = fminf(ay2, by2);
                    float iw = fmaxf(xx2 - xx1 + 1.f, 0.f);
                    float ih = fmaxf(yy2 - yy1 + 1.f, 0.f);
                    float inter = iw * ih;
                    s = inter / (aarea + area - inter) > NMS_T;
                }
                sup |= __ballot(s);
            }
            bool kept = valid && !((sup >> lane) & 1ULL);
            unsigned long long keptm = __ballot(kept);
            int rank = __popcll(keptm & ((1ULL << lane) - 1ULL));
            if (kept && rank < DETS) {
                int slot = pid * DETS + rank;
                out_score[slot] = __uint_as_float((unsigned)(k >> 32));
                out_key[slot] = (unsigned)(c * NPI + lane);
                out_box[slot * 4 + 0] = bx1; out_box[slot * 4 + 1] = by1;
                out_box[slot * 4 + 2] = bx2; out_box[slot * 4 + 3] = by2;
            }
            if (lane == 0) {
                int tot = __popcll(keptm);
                out_cnt[pid] = tot < DETS ? tot : DETS;
            }
        }
        return;
    }

    int P = 2;
    while (P < n) P <<= 1;
    for (int k = 2; k <= P; k <<= 1) {
        for (int j = k >> 1; j > 0; j >>= 1) {
            for (int i = t; i < P; i += 256) {
                int ixj = i ^ j;
                if (ixj > i) {
                    unsigned long long a = sp.key[i], b = sp.key[ixj];
                    bool up = (i & k) == 0;
                    if (up ? (a < b) : (a > b)) { sp.key[i] = b; sp.key[ixj] = a; }
                }
            }
            __syncthreads();
        }
    }
    for (int i = t; i < NPI; i += 256) sp.keep[i] = 0;
    __syncthreads();

    if (n <= FASTN) {
        for (int i = t; i < n; i += 256) {
            int mi = NPI - 1 - (int)(sp.key[i] & 0xFFFFFFFFu);
            float bx1 = sp.box[mi][0], by1 = sp.box[mi][1];
            float bx2 = sp.box[mi][2], by2 = sp.box[mi][3];
            sp.sbox[i][0] = bx1; sp.sbox[i][1] = by1;
            sp.sbox[i][2] = bx2; sp.sbox[i][3] = by2;
            sp.sarea[i] = (bx2 - bx1 + 1.f) * (by2 - by1 + 1.f);
        }
        __syncthreads();
        int nwords = ((n + 63) >> 6);
        for (int w = t; w < n * (FASTN/64); w += 256) {
            int i = w >> 2, wb = w & 3;
            if (wb >= nwords || ((wb + 1) << 6) - 1 <= i) { sp.mask[i][wb] = 0ULL; continue; }
            float ax1 = sp.sbox[i][0], ay1 = sp.sbox[i][1];
            float ax2 = sp.sbox[i][2], ay2 = sp.sbox[i][3];
            float aarea = sp.sarea[i];
            unsigned long long bits = 0ULL;
            int jbase = wb << 6;
            #pragma unroll 4
            for (int b = 0; b < 64; ++b) {
                int j = jbase + b;
                if (j < n && j > i) {
                    float bx1 = sp.sbox[j][0], by1 = sp.sbox[j][1];
                    float bx2 = sp.sbox[j][2], by2 = sp.sbox[j][3];
                    float xx1 = fmaxf(ax1, bx1), yy1 = fmaxf(ay1, by1);
                    float xx2 = fminf(ax2, bx2), yy2 = fminf(ay2, by2);
                    float iw = fmaxf(xx2 - xx1 + 1.f, 0.f);
                    float ih = fmaxf(yy2 - yy1 + 1.f, 0.f);
                    float inter = iw * ih;
                    if (inter / (aarea + sp.sarea[j] - inter) > NMS_T) bits |= (1ULL << b);
                }
            }
            sp.mask[i][wb] = bits;
        }
        __syncthreads();
        if (t < 64) {
            int lane = t;
            unsigned long long kb = 0ULL;
            if (lane < 4) {
                int rem = n - (lane << 6);
                if (rem >= 64) kb = ~0ULL;
                else if (rem > 0) kb = (1ULL << rem) - 1ULL;
            }
            unsigned long long rm = 0ULL;
            for (int i = 0; i < n; ++i) {
                unsigned long long rw = __shfl(rm, i >> 6, 64);
                if (!((rw >> (i & 63)) & 1ULL)) {
                    unsigned long long mrow = (lane < 4) ? sp.mask[i][lane] : 0ULL;
                    rm |= mrow;
                }
            }
            if (lane < 4) sp.keepw[lane] = kb & ~rm;
        }
        __syncthreads();
        for (int i = t; i < n; i += 256)
            sp.keep[i] = (int)((sp.keepw[i >> 6] >> (i & 63)) & 1ULL);
        __syncthreads();
    } else {
        for (int i = t; i < n; i += 256) sp.keep[i] = 1;
        __syncthreads();
        for (int i = 0; i < n; ++i) {
            if (sp.keep[i]) {
                unsigned long long ki = sp.key[i];
                int mi = NPI - 1 - (int)(ki & 0xFFFFFFFFu);
                float ax1 = sp.box[mi][0], ay1 = sp.box[mi][1];
                float ax2 = sp.box[mi][2], ay2 = sp.box[mi][3];
                float aarea = (ax2 - ax1 + 1.f) * (ay2 - ay1 + 1.f);
                for (int jj = i + 1 + t; jj < n; jj += 256) {
                    if (sp.keep[jj]) {
                        int mj = NPI - 1 - (int)(sp.key[jj] & 0xFFFFFFFFu);
                        float bx1 = sp.box[mj][0], by1 = sp.box[mj][1];
                        float bx2 = sp.box[mj][2], by2 = sp.box[mj][3];
                        float xx1 = fmaxf(ax1, bx1), yy1 = fmaxf(ay1, by1);
                        float xx2 = fminf(ax2, bx2), yy2 = fminf(ay2, by2);
                        float iw = fmaxf(xx2 - xx1 + 1.f, 0.f);
                        float ih = fmaxf(yy2 - yy1 + 1.f, 0.f);
                        float inter = iw * ih;
                        float barea = (bx2 - bx1 + 1.f) * (by2 - by1 + 1.f);
                        if (inter / (aarea + barea - inter) > NMS_T) sp.keep[jj] = 0;
                    }
                }
            }
            __syncthreads();
        }
    }
    {
        int lane = t & 63, w = t >> 6;
        int k0 = sp.keep[4 * t], k1 = sp.keep[4 * t + 1];
        int k2 = sp.keep[4 * t + 2], k3 = sp.keep[4 * t + 3];
        unsigned s = (unsigned)(k0 + k1 + k2 + k3);
        unsigned v = s;
        #pragma unroll
        for (int off = 1; off < 64; off <<= 1) {
            unsigned u = __shfl_up(v, off, 64);
            v += (lane >= off) ? u : 0u;
        }
        if (lane == 63) sp.wpre[w] = v;
        __syncthreads();
        unsigned woff = 0;
        for (int w2 = 0; w2 < w; ++w2) woff += sp.wpre[w2];
        unsigned r = v + woff - s;
        #pragma unroll
        for (int j = 0; j < 4; ++j) {
            int i = 4 * t + j;
            int kv = (j == 0) ? k0 : (j == 1) ? k1 : (j == 2) ? k2 : k3;
            if (kv && r < DETS) {
                unsigned long long ki = sp.key[i];
                int mi = NPI - 1 - (int)(ki & 0xFFFFFFFFu);
                int slot = pid * DETS + (int)r;
                out_score[slot] = __uint_as_float((unsigned)(ki >> 32));
                out_key[slot] = (unsigned)(c * NPI + i);
                out_box[slot * 4 + 0] = sp.box[mi][0];
                out_box[slot * 4 + 1] = sp.box[mi][1];
                out_box[slot * 4 + 2] = sp.box[mi][2];
                out_box[slot * 4 + 3] = sp.box[mi][3];
            }
            r += (unsigned)kv;
        }
        __syncthreads();
        if (t == 0) {
            unsigned tot = sp.wpre[0] + sp.wpre[1] + sp.wpre[2] + sp.wpre[3];
            out_cnt[pid] = (int)(tot < DETS ? tot : DETS);
        }
    }
}

// ---------------- Kernel 3: per-image top-100, radix-select + rank write ----------
__device__ __forceinline__ void suffix_select256(
    unsigned* hist, unsigned* wtot, int K, int* outB, unsigned* outAbove)
{
    int t = threadIdx.x, lane = t & 63, w = t >> 6;
    unsigned loc[16]; unsigned ps = 0;
    #pragma unroll
    for (int j = 0; j < 16; ++j) { loc[j] = hist[t * 16 + j]; ps += loc[j]; }
    unsigned v = ps;
    #pragma unroll
    for (int off = 1; off < 64; off <<= 1) {
        unsigned u = __shfl_down(v, off, 64);
        v += (lane + off < 64) ? u : 0u;
    }
    if (lane == 0) wtot[w] = v;
    __syncthreads();
    unsigned woff = 0;
    for (int w2 = w + 1; w2 < 4; ++w2) woff += wtot[w2];
    unsigned base = v + woff - ps;
    unsigned suf = 0;
    #pragma unroll
    for (int j = 15; j >= 0; --j) {
        unsigned A = base + suf;
        if ((int)A < K && (int)(A + loc[j]) >= K) { *outB = t * 16 + j; *outAbove = A; }
        suf += loc[j];
    }
    __syncthreads();
}

__global__ __launch_bounds__(256) void topk_merge(
    const int* __restrict__ cnts, const float* __restrict__ escore,
    const unsigned* __restrict__ ekey, const float* __restrict__ ebox,
    float* __restrict__ out)
{
    int img = blockIdx.x;
    __shared__ unsigned sc[NCAND];
    __shared__ unsigned hist[4096];
    __shared__ unsigned long long cand[CAND_CAP];
    __shared__ int scnts[NFG];
    __shared__ unsigned wtot[4];
    __shared__ int sB1, sB2, sNc;
    __shared__ unsigned sAb1, sAb2;

    int t = threadIdx.x;
    if (t < NFG) scnts[t] = cnts[img * NFG + t];
    if (t == 0) { sB1 = 0; sB2 = 0; sNc = 0; sAb1 = 0; sAb2 = 0; }
    for (int i = t; i < 4096; i += 256) hist[i] = 0;
    __syncthreads();

    for (int p = t; p < NCAND; p += 256) {
        unsigned fb = 0;
        if ((p % DETS) < scnts[p / DETS]) fb = __float_as_uint(escore[img * NCAND + p]);
        sc[p] = fb;
        if (fb) atomicAdd(&hist[fb >> 19], 1u);
    }
    __syncthreads();
    suffix_select256(hist, wtot, DETS, &sB1, &sAb1);
    int B1 = sB1; unsigned ab1 = sAb1;

    for (int i = t; i < 4096; i += 256) hist[i] = 0;
    __syncthreads();
    for (int p = t; p < NCAND; p += 256) {
        unsigned fb = sc[p];
        if (fb && (int)(fb >> 19) == B1) atomicAdd(&hist[(fb >> 7) & 0xFFFu], 1u);
    }
    __syncthreads();
    suffix_select256(hist, wtot, DETS - (int)ab1, &sB2, &sAb2);
    int B2 = sB2;

    for (int p = t; p < NCAND; p += 256) {
        unsigned fb = sc[p];
        if (fb) {
            int d1 = (int)(fb >> 19);
            bool ok = d1 > B1 || (d1 == B1 && (int)((fb >> 7) & 0xFFFu) >= B2);
            if (ok) {
                int pos = atomicAdd(&sNc, 1);
                if (pos < CAND_CAP) {
                    unsigned fk = ekey[img * NCAND + p];
                    cand[pos] = ((unsigned long long)fb << 32)
                              | (((0x1FFFFu - fk) << 13) | (unsigned)p);
                }
            }
        }
    }
    __syncthreads();
    int nc = sNc < CAND_CAP ? sNc : CAND_CAP;

    float* oScore = out;
    float* oBox   = out + NIMG * DETS;
    float* oLab   = out + NIMG * DETS * 5;

    for (int k = t; k < DETS; k += 256) {
        if (k >= nc) {
            int o = img * DETS + k;
            oScore[o] = 0.f;
            oBox[o * 4 + 0] = 0.f; oBox[o * 4 + 1] = 0.f;
            oBox[o * 4 + 2] = 0.f; oBox[o * 4 + 3] = 0.f;
            oLab[o] = 0.f;
        }
    }

    // rank-order direct write: rank = #{cand > mine}; keys unique
    for (int i = t; i < nc; i += 256) {
        unsigned long long ki = cand[i];
        int r = 0;
        for (int j = 0; j < nc; ++j) r += (cand[j] > ki) ? 1 : 0;
        if (r < DETS) {
            float scv = __uint_as_float((unsigned)(ki >> 32));
            unsigned low = (unsigned)(ki & 0xFFFFFFFFu);
            unsigned flatkey = 0x1FFFFu - ((low >> 13) & 0x1FFFFu);
            int p = (int)(low & 0x1FFFu);
            int gp = img * NCAND + p;
            int o = img * DETS + r;
            oScore[o] = scv;
            oBox[o * 4 + 0] = ebox[gp * 4 + 0];
            oBox[o * 4 + 1] = ebox[gp * 4 + 1];
            oBox[o * 4 + 2] = ebox[gp * 4 + 2];
            oBox[o * 4 + 3] = ebox[gp * 4 + 3];
            oLab[o] = (float)((flatkey >> 10) + 1);
        }
    }
}

extern "C" void kernel_launch(void* const* d_in, const int* in_sizes, int n_in,
                              void* d_out, int out_size, void* d_ws, size_t ws_size,
                              hipStream_t stream) {
    const float* logits = (const float*)d_in[0];
    const float* boxreg = (const float*)d_in[1];
    const float* props  = (const float*)d_in[2];
    const int*   hptr   = (const int*)d_in[3];
    const int*   wptr   = (const int*)d_in[4];
    float* out = (float*)d_out;
    int M = in_sizes[0] / NCLS; // 8192

    char* ws = (char*)d_ws;
    float*    probT  = (float*)ws;    ws += (size_t)NFG * M * sizeof(float);
    int*      gcnt   = (int*)ws;      ws += (size_t)NIMG * NFG * sizeof(int);
    float*    escore = (float*)ws;    ws += (size_t)NIMG * NCAND * sizeof(float);
    unsigned* ekey   = (unsigned*)ws; ws += (size_t)NIMG * NCAND * sizeof(unsigned);
    float*    ebox   = (float*)ws;    ws += (size_t)NIMG * NCAND * 4 * sizeof(float);

    softmax_probT<<<M / ROWS, 256, 0, stream>>>(logits, probT, M);
    per_class_nms<<<NIMG * NFG, 256, 0, stream>>>(
        probT, boxreg, props, hptr, wptr, gcnt, escore, ekey, ebox, M);
    topk_merge<<<NIMG, 256, 0, stream>>>(gcnt, escore, ekey, ebox, out);
}

// Round 13
// 61.283 us; speedup vs baseline: 1.8970x; 1.1878x over previous
//
#include <hip/hip_runtime.h>
#include <stdint.h>
#include <math.h>

#define NCLS 81
#define NFG  80
#define NPI  1024
#define NIMG 8
#define DETS 100
#define SCORE_T 0.05f
#define NMS_T   0.5f
#define NCAND   (NFG * DETS)   // 8000
#define CAND_CAP 2048
#define FASTN 256              // block bitmask-NMS path limit
#define ROWS 64                // rows per softmax block

static constexpr float BBOX_CLIP = 4.1351665567423557f; // log(1000/16)

// ---------------- Kernel 1: softmax -> transposed prob matrix ----------------
// probT[c][row], c = fg class index 0..79 (class c+1), row = 0..M-1.
__global__ __launch_bounds__(256) void softmax_probT(
    const float* __restrict__ logits, float* __restrict__ probT, int M)
{
    __shared__ float tile[ROWS * NCLS];   // 20736 B
    __shared__ float mx[ROWS], dn[ROWS];
    int t = threadIdx.x;
    int rbase = blockIdx.x * ROWS;

    for (int idx = t; idx < ROWS * NCLS; idx += 256)
        tile[idx] = logits[(size_t)rbase * NCLS + idx];
    __syncthreads();

    if (t < ROWS) {
        const float* r = tile + t * NCLS;
        float m = r[0];
        #pragma unroll
        for (int j = 1; j < NCLS; ++j) m = fmaxf(m, r[j]);
        float s = 0.f;
        #pragma unroll
        for (int j = 0; j < NCLS; ++j) s += expf(r[j] - m);
        mx[t] = m; dn[t] = s;
    }
    __syncthreads();

    for (int o = t; o < ROWS * NFG; o += 256) {
        int r = o & 63;
        int c = o >> 6;                         // 0..79
        float v = expf(tile[r * NCLS + (c + 1)] - mx[r]) / dn[r];
        probT[(size_t)c * M + rbase + r] = v;   // coalesced 256B segments
    }
}

// ---------------- Kernel 2: per-(image,class) NMS ----------------
__global__ __launch_bounds__(256) void per_class_nms(
    const float* __restrict__ probT, const float* __restrict__ boxreg,
    const float* __restrict__ props, const int* __restrict__ hptr,
    const int* __restrict__ wptr, int* __restrict__ out_cnt,
    float* __restrict__ out_score, unsigned* __restrict__ out_key,
    float* __restrict__ out_box, int M)
{
    int pid = blockIdx.x;           // 0..639
    int img = pid / NFG;
    int c   = pid % NFG;            // fg class row; label = c+1
    int cls = c + 1;

    __shared__ float box_lds[NPI][4];               // 16KB (by proposal id)
    __shared__ unsigned long long key[NPI];         // 8KB
    __shared__ int keep[NPI];                       // 4KB
    __shared__ float sbox[FASTN][4];                // 4KB (sorted order)
    __shared__ float sarea[FASTN];                  // 1KB
    __shared__ unsigned long long mask[FASTN][FASTN/64]; // 8KB
    __shared__ unsigned long long keepw[FASTN/64];
    __shared__ unsigned wpre[4];
    __shared__ int cnt;

    int t = threadIdx.x;
    float W1 = (float)(*wptr - 1);
    float H1 = (float)(*hptr - 1);

    if (t == 0) cnt = 0;
    for (int i = t; i < NPI; i += 256) key[i] = 0ULL;
    __syncthreads();

    // ---- load phase: coalesced float4 prob read, decode passing proposals ----
    {
        const float4 pv = *(const float4*)(probT + (size_t)c * M + img * NPI + 4 * t);
        float pr[4] = {pv.x, pv.y, pv.z, pv.w};
        #pragma unroll
        for (int j = 0; j < 4; ++j) {
            if (pr[j] > SCORE_T) {
                int m = 4 * t + j;
                int g = img * NPI + m;
                const float4 pb = *(const float4*)(props + (size_t)g * 4);
                float x1 = pb.x, y1 = pb.y, x2 = pb.z, y2 = pb.w;
                float w  = x2 - x1 + 1.0f, h = y2 - y1 + 1.0f;
                float cx = x1 + 0.5f * w,  cy = y1 + 0.5f * h;
                const float4 rc = *(const float4*)(boxreg + (size_t)g * (4 * NCLS) + 4 * cls);
                float dx = rc.x / 10.0f, dy = rc.y / 10.0f;
                float dw = fminf(rc.z / 5.0f, BBOX_CLIP);
                float dh = fminf(rc.w / 5.0f, BBOX_CLIP);
                float pcx = dx * w + cx, pcy = dy * h + cy;
                float pw = expf(dw) * w, ph = expf(dh) * h;
                float bx1 = pcx - 0.5f * pw;
                float by1 = pcy - 0.5f * ph;
                float bx2 = pcx + 0.5f * pw - 1.0f;
                float by2 = pcy + 0.5f * ph - 1.0f;
                bx1 = fminf(fmaxf(bx1, 0.f), W1);
                bx2 = fminf(fmaxf(bx2, 0.f), W1);
                by1 = fminf(fmaxf(by1, 0.f), H1);
                by2 = fminf(fmaxf(by2, 0.f), H1);
                box_lds[m][0] = bx1; box_lds[m][1] = by1;
                box_lds[m][2] = bx2; box_lds[m][3] = by2;
                int p = atomicAdd(&cnt, 1);
                unsigned fb = __float_as_uint(pr[j]);
                key[p] = ((unsigned long long)fb << 32) | (unsigned)(NPI - 1 - m);
            }
        }
    }
    __syncthreads();
    int n = cnt;

    // ================= wave fast path: n <= 64, zero further syncs =================
    if (n <= 64) {
        if (t < 64) {
            int lane = t;
            unsigned long long k = (lane < n) ? key[lane] : 0ULL;
            // bitonic sort descending across 64 lanes (keys unique or 0)
            #pragma unroll
            for (int kk = 2; kk <= 64; kk <<= 1) {
                #pragma unroll
                for (int j = kk >> 1; j > 0; j >>= 1) {
                    unsigned long long o = __shfl_xor(k, j, 64);
                    bool up = ((lane & kk) == 0);
                    bool lower = ((lane & j) == 0);
                    bool take_max = (up == lower);
                    k = take_max ? (k > o ? k : o) : (k < o ? k : o);
                }
            }
            bool valid = (lane < n);
            float bx1 = 0.f, by1 = 0.f, bx2 = 0.f, by2 = 0.f, area = 0.f;
            if (valid) {
                int mi = NPI - 1 - (int)(k & 0xFFFFFFFFu);
                bx1 = box_lds[mi][0]; by1 = box_lds[mi][1];
                bx2 = box_lds[mi][2]; by2 = box_lds[mi][3];
                area = (bx2 - bx1 + 1.f) * (by2 - by1 + 1.f);
            }
            unsigned long long sup = 0ULL;
            for (int i = 0; i < n; ++i) {
                bool alive = !((sup >> i) & 1ULL);
                float ax1 = __shfl(bx1, i, 64), ay1 = __shfl(by1, i, 64);
                float ax2 = __shfl(bx2, i, 64), ay2 = __shfl(by2, i, 64);
                float aarea = __shfl(area, i, 64);
                bool s = false;
                if (alive && valid && lane > i) {
                    float xx1 = fmaxf(ax1, bx1), yy1 = fmaxf(ay1, by1);
                    float xx2 = fminf(ax2, bx2), yy2 = fminf(ay2, by2);
                    float iw = fmaxf(xx2 - xx1 + 1.f, 0.f);
                    float ih = fmaxf(yy2 - yy1 + 1.f, 0.f);
                    float inter = iw * ih;
                    float iou = inter / (aarea + area - inter);
                    s = iou > NMS_T;
                }
                sup |= __ballot(s);
            }
            bool kept = valid && !((sup >> lane) & 1ULL);
            unsigned long long keptm = __ballot(kept);
            int rank = __popcll(keptm & ((1ULL << lane) - 1ULL));
            if (kept && rank < DETS) {
                int slot = pid * DETS + rank;
                out_score[slot] = __uint_as_float((unsigned)(k >> 32));
                out_key[slot] = (unsigned)(c * NPI + lane);
                out_box[slot * 4 + 0] = bx1;
                out_box[slot * 4 + 1] = by1;
                out_box[slot * 4 + 2] = bx2;
                out_box[slot * 4 + 3] = by2;
            }
            if (lane == 0) {
                int tot = __popcll(keptm);
                out_cnt[pid] = tot < DETS ? tot : DETS;
            }
        }
        return;
    }

    // ================= block paths: n > 64 =================
    int P = 2;
    while (P < n) P <<= 1;
    for (int k = 2; k <= P; k <<= 1) {
        for (int j = k >> 1; j > 0; j >>= 1) {
            for (int i = t; i < P; i += 256) {
                int ixj = i ^ j;
                if (ixj > i) {
                    unsigned long long a = key[i], b = key[ixj];
                    bool up = (i & k) == 0;
                    if (up ? (a < b) : (a > b)) { key[i] = b; key[ixj] = a; }
                }
            }
            __syncthreads();
        }
    }

    for (int i = t; i < NPI; i += 256) keep[i] = 0;
    __syncthreads();

    if (n <= FASTN) {
        // ---------- bitmask NMS ----------
        for (int i = t; i < n; i += 256) {
            int mi = NPI - 1 - (int)(key[i] & 0xFFFFFFFFu);
            float bx1 = box_lds[mi][0], by1 = box_lds[mi][1];
            float bx2 = box_lds[mi][2], by2 = box_lds[mi][3];
            sbox[i][0] = bx1; sbox[i][1] = by1; sbox[i][2] = bx2; sbox[i][3] = by2;
            sarea[i] = (bx2 - bx1 + 1.f) * (by2 - by1 + 1.f);
        }
        __syncthreads();
        int nwords = ((n + 63) >> 6);
        for (int w = t; w < n * (FASTN/64); w += 256) {
            int i = w >> 2, wb = w & 3;
            if (wb >= nwords || ((wb + 1) << 6) - 1 <= i) { mask[i][wb] = 0ULL; continue; }
            float ax1 = sbox[i][0], ay1 = sbox[i][1];
            float ax2 = sbox[i][2], ay2 = sbox[i][3];
            float aarea = sarea[i];
            unsigned long long bits = 0ULL;
            int jbase = wb << 6;
            #pragma unroll 4
            for (int b = 0; b < 64; ++b) {
                int j = jbase + b;
                if (j < n && j > i) {
                    float bx1 = sbox[j][0], by1 = sbox[j][1];
                    float bx2 = sbox[j][2], by2 = sbox[j][3];
                    float xx1 = fmaxf(ax1, bx1), yy1 = fmaxf(ay1, by1);
                    float xx2 = fminf(ax2, bx2), yy2 = fminf(ay2, by2);
                    float iw = fmaxf(xx2 - xx1 + 1.f, 0.f);
                    float ih = fmaxf(yy2 - yy1 + 1.f, 0.f);
                    float inter = iw * ih;
                    float iou = inter / (aarea + sarea[j] - inter);
                    if (iou > NMS_T) bits |= (1ULL << b);
                }
            }
            mask[i][wb] = bits;
        }
        __syncthreads();
        if (t < 64) {
            int lane = t;
            unsigned long long kb = 0ULL;
            if (lane < 4) {
                int rem = n - (lane << 6);
                if (rem >= 64) kb = ~0ULL;
                else if (rem > 0) kb = (1ULL << rem) - 1ULL;
            }
            unsigned long long rm = 0ULL;
            for (int i = 0; i < n; ++i) {
                unsigned long long rw = __shfl(rm, i >> 6, 64);
                if (!((rw >> (i & 63)) & 1ULL)) {
                    unsigned long long mrow = (lane < 4) ? mask[i][lane] : 0ULL;
                    rm |= mrow;
                }
            }
            if (lane < 4) keepw[lane] = kb & ~rm;
        }
        __syncthreads();
        for (int i = t; i < n; i += 256)
            keep[i] = (int)((keepw[i >> 6] >> (i & 63)) & 1ULL);
        __syncthreads();
    } else {
        // ---------- serial greedy ----------
        for (int i = t; i < n; i += 256) keep[i] = 1;
        __syncthreads();
        for (int i = 0; i < n; ++i) {
            if (keep[i]) {
                unsigned long long ki = key[i];
                int mi = NPI - 1 - (int)(ki & 0xFFFFFFFFu);
                float ax1 = box_lds[mi][0], ay1 = box_lds[mi][1];
                float ax2 = box_lds[mi][2], ay2 = box_lds[mi][3];
                float aarea = (ax2 - ax1 + 1.f) * (ay2 - ay1 + 1.f);
                for (int jj = i + 1 + t; jj < n; jj += 256) {
                    if (keep[jj]) {
                        int mj = NPI - 1 - (int)(key[jj] & 0xFFFFFFFFu);
                        float bx1 = box_lds[mj][0], by1 = box_lds[mj][1];
                        float bx2 = box_lds[mj][2], by2 = box_lds[mj][3];
                        float xx1 = fmaxf(ax1, bx1), yy1 = fmaxf(ay1, by1);
                        float xx2 = fminf(ax2, bx2), yy2 = fminf(ay2, by2);
                        float iw = fmaxf(xx2 - xx1 + 1.f, 0.f);
                        float ih = fmaxf(yy2 - yy1 + 1.f, 0.f);
                        float inter = iw * ih;
                        float barea = (bx2 - bx1 + 1.f) * (by2 - by1 + 1.f);
                        float iou = inter / (aarea + barea - inter);
                        if (iou > NMS_T) keep[jj] = 0;
                    }
                }
            }
            __syncthreads();
        }
    }

    // ---------- parallel compaction via block prefix scan ----------
    {
        int lane = t & 63, w = t >> 6;
        int k0 = keep[4 * t], k1 = keep[4 * t + 1];
        int k2 = keep[4 * t + 2], k3 = keep[4 * t + 3];
        unsigned s = (unsigned)(k0 + k1 + k2 + k3);
        unsigned v = s;
        #pragma unroll
        for (int off = 1; off < 64; off <<= 1) {
            unsigned u = __shfl_up(v, off, 64);
            v += (lane >= off) ? u : 0u;
        }
        if (lane == 63) wpre[w] = v;
        __syncthreads();
        unsigned woff = 0;
        for (int w2 = 0; w2 < w; ++w2) woff += wpre[w2];
        unsigned before = v + woff - s;
        unsigned r = before;
        #pragma unroll
        for (int j = 0; j < 4; ++j) {
            int i = 4 * t + j;
            int kv = (j == 0) ? k0 : (j == 1) ? k1 : (j == 2) ? k2 : k3;
            if (kv && r < DETS) {
                unsigned long long ki = key[i];
                int mi = NPI - 1 - (int)(ki & 0xFFFFFFFFu);
                int slot = pid * DETS + (int)r;
                out_score[slot] = __uint_as_float((unsigned)(ki >> 32));
                out_key[slot] = (unsigned)(c * NPI + i);
                out_box[slot * 4 + 0] = box_lds[mi][0];
                out_box[slot * 4 + 1] = box_lds[mi][1];
                out_box[slot * 4 + 2] = box_lds[mi][2];
                out_box[slot * 4 + 3] = box_lds[mi][3];
            }
            r += (unsigned)kv;
        }
        __syncthreads();
        if (t == 0) {
            unsigned tot = wpre[0] + wpre[1] + wpre[2] + wpre[3];
            out_cnt[pid] = (int)(tot < DETS ? tot : DETS);
        }
    }
}

// ---------------- Kernel 3: per-image top-100 via radix-select ----------------
__device__ __forceinline__ void suffix_select(
    unsigned* hist, unsigned* wtot, int K, int* outB, unsigned* outAbove)
{
    int t = threadIdx.x, lane = t & 63, w = t >> 6;
    unsigned c0 = hist[4 * t], c1 = hist[4 * t + 1];
    unsigned c2 = hist[4 * t + 2], c3 = hist[4 * t + 3];
    unsigned ps = c0 + c1 + c2 + c3;
    unsigned v = ps;
    #pragma unroll
    for (int off = 1; off < 64; off <<= 1) {
        unsigned u = __shfl_down(v, off, 64);
        v += (lane + off < 64) ? u : 0u;
    }
    if (lane == 0) wtot[w] = v;
    __syncthreads();
    unsigned woff = 0;
    for (int w2 = w + 1; w2 < 16; ++w2) woff += wtot[w2];
    unsigned Sown = v + woff;
    unsigned A3 = Sown - ps;
    unsigned A2 = A3 + c3, A1 = A2 + c2, A0 = A1 + c1;
    unsigned A[4] = {A0, A1, A2, A3};
    unsigned C[4] = {c0, c1, c2, c3};
    #pragma unroll
    for (int j = 0; j < 4; ++j) {
        if ((int)A[j] < K && (int)(A[j] + C[j]) >= K) {
            *outB = 4 * t + j;
            *outAbove = A[j];
        }
    }
    __syncthreads();
}

__global__ __launch_bounds__(1024) void topk_merge(
    const int* __restrict__ cnts, const float* __restrict__ escore,
    const unsigned* __restrict__ ekey, const float* __restrict__ ebox,
    float* __restrict__ out)
{
    int img = blockIdx.x;
    __shared__ unsigned sc[NCAND];
    __shared__ unsigned hist[4096];
    __shared__ unsigned long long cand[CAND_CAP];
    __shared__ unsigned wtot[16];
    __shared__ int sB1, sB2, sNc;
    __shared__ unsigned sAb1, sAb2;

    int t = threadIdx.x;
    if (t == 0) { sB1 = 0; sB2 = 0; sNc = 0; sAb1 = 0; sAb2 = 0; }
    for (int p = t; p < NCAND; p += 1024) {
        int cc = p / DETS, k = p % DETS;
        unsigned fb = 0;
        if (k < cnts[img * NFG + cc]) fb = __float_as_uint(escore[img * NCAND + p]);
        sc[p] = fb;
    }
    for (int i = t; i < 4096; i += 1024) hist[i] = 0;
    __syncthreads();

    for (int p = t; p < NCAND; p += 1024) {
        unsigned fb = sc[p];
        if (fb) atomicAdd(&hist[fb >> 19], 1u);
    }
    __syncthreads();
    suffix_select(hist, wtot, DETS, &sB1, &sAb1);
    int B1 = sB1;
    unsigned ab1 = sAb1;

    for (int i = t; i < 4096; i += 1024) hist[i] = 0;
    __syncthreads();
    for (int p = t; p < NCAND; p += 1024) {
        unsigned fb = sc[p];
        if (fb && (int)(fb >> 19) == B1) atomicAdd(&hist[(fb >> 7) & 0xFFFu], 1u);
    }
    __syncthreads();
    suffix_select(hist, wtot, DETS - (int)ab1, &sB2, &sAb2);
    int B2 = sB2;

    for (int p = t; p < NCAND; p += 1024) {
        unsigned fb = sc[p];
        if (fb) {
            int d1 = (int)(fb >> 19);
            bool ok = d1 > B1 || (d1 == B1 && (int)((fb >> 7) & 0xFFFu) >= B2);
            if (ok) {
                int pos = atomicAdd(&sNc, 1);
                if (pos < CAND_CAP) {
                    unsigned fk = ekey[img * NCAND + p];
                    unsigned low = ((0x1FFFFu - fk) << 13) | (unsigned)p;
                    cand[pos] = ((unsigned long long)fb << 32) | low;
                }
            }
        }
    }
    __syncthreads();
    int nc = sNc < CAND_CAP ? sNc : CAND_CAP;
    int P = 128;
    while (P < nc) P <<= 1;
    for (int i = t; i < P; i += 1024)
        if (i >= nc) cand[i] = 0ULL;
    __syncthreads();

    for (int k = 2; k <= P; k <<= 1) {
        for (int j = k >> 1; j > 0; j >>= 1) {
            for (int i = t; i < P; i += 1024) {
                int ixj = i ^ j;
                if (ixj > i) {
                    unsigned long long a = cand[i], b = cand[ixj];
                    bool up = (i & k) == 0;
                    if (up ? (a < b) : (a > b)) { cand[i] = b; cand[ixj] = a; }
                }
            }
            __syncthreads();
        }
    }

    float* oScore = out;
    float* oBox   = out + NIMG * DETS;
    float* oLab   = out + NIMG * DETS * 5;

    if (t < DETS) {
        unsigned long long b = cand[t];
        int o = img * DETS + t;
        if (b != 0ULL) {
            float scv = __uint_as_float((unsigned)(b >> 32));
            unsigned low = (unsigned)(b & 0xFFFFFFFFu);
            unsigned flatkey = 0x1FFFFu - ((low >> 13) & 0x1FFFFu);
            int p = (int)(low & 0x1FFFu);
            int gp = img * NCAND + p;
            oScore[o] = scv;
            oBox[o * 4 + 0] = ebox[gp * 4 + 0];
            oBox[o * 4 + 1] = ebox[gp * 4 + 1];
            oBox[o * 4 + 2] = ebox[gp * 4 + 2];
            oBox[o * 4 + 3] = ebox[gp * 4 + 3];
            oLab[o] = (float)((flatkey >> 10) + 1);
        } else {
            oScore[o] = 0.f;
            oBox[o * 4 + 0] = 0.f; oBox[o * 4 + 1] = 0.f;
            oBox[o * 4 + 2] = 0.f; oBox[o * 4 + 3] = 0.f;
            oLab[o] = 0.f;
        }
    }
}

extern "C" void kernel_launch(void* const* d_in, const int* in_sizes, int n_in,
                              void* d_out, int out_size, void* d_ws, size_t ws_size,
                              hipStream_t stream) {
    const float* logits = (const float*)d_in[0];
    const float* boxreg = (const float*)d_in[1];
    const float* props  = (const float*)d_in[2];
    const int*   hptr   = (const int*)d_in[3];
    const int*   wptr   = (const int*)d_in[4];
    float* out = (float*)d_out;
    int M = in_sizes[0] / NCLS; // 8192

    char* ws = (char*)d_ws;
    float*    probT  = (float*)ws;    ws += (size_t)NFG * M * sizeof(float);
    int*      cnt    = (int*)ws;      ws += (size_t)NIMG * NFG * sizeof(int);
    float*    escore = (float*)ws;    ws += (size_t)NIMG * NCAND * sizeof(float);
    unsigned* ekey   = (unsigned*)ws; ws += (size_t)NIMG * NCAND * sizeof(unsigned);
    float*    ebox   = (float*)ws;    ws += (size_t)NIMG * NCAND * 4 * sizeof(float);

    softmax_probT<<<M / ROWS, 256, 0, stream>>>(logits, probT, M);
    per_class_nms<<<NIMG * NFG, 256, 0, stream>>>(
        probT, boxreg, props, hptr, wptr, cnt, escore, ekey, ebox, M);
    topk_merge<<<NIMG, 1024, 0, stream>>>(cnt, escore, ekey, ebox, out);
}